// Round 8
// baseline (356.909 us; speedup 1.0000x reference)
//
#include <hip/hip_runtime.h>
#include <math.h>

#define FDIM 128
#define RPB 256      // rows per bucket (bucket = id >> 8)
#define NBLK 512     // blocks in scatter
#define MAXB 512     // max buckets (N <= 131072)
#define CAPB 32      // slots per (bucket, block) private segment: mean 8, 4x headroom
#define CAP (NBLK * CAPB)   // 16384 slots per bucket

typedef __attribute__((ext_vector_type(8))) short short8;   // 8 bf16 (4 VGPRs)
typedef __attribute__((ext_vector_type(4))) float floatx4;  // 4 fp32 acc

static __device__ __forceinline__ unsigned short f2bf(float f) {
    unsigned int u = __float_as_uint(f);
    u = (u + 0x7fff + ((u >> 16) & 1)) >> 16;   // round-to-nearest-even
    return (unsigned short)u;
}

static __device__ __forceinline__ unsigned int cvtpk(float a, float b) {
    // packed f32->bf16 RNE: dst.lo = bf16(a), dst.hi = bf16(b)
    unsigned int r;
    asm("v_cvt_pk_bf16_f32 %0, %1, %2" : "=v"(r) : "v"(a), "v"(b));
    return r;
}

static __device__ __forceinline__ void bf2f(unsigned int u, float& a, float& b) {
    a = __uint_as_float(u << 16);
    b = __uint_as_float(u & 0xffff0000u);
}

// ---------------- fused init: zero hs row N, convert W (no counters needed anymore) ----------------

__global__ __launch_bounds__(256) void k_init(unsigned int* hsz,
                                              const float* __restrict__ W0, const float* __restrict__ W1,
                                              unsigned short* __restrict__ W0t, unsigned short* __restrict__ W1t) {
    const int b = blockIdx.x;
    const int tid = threadIdx.x;
    const float* W = (b == 0) ? W0 : W1;
    unsigned short* Wt = (b == 0) ? W0t : W1t;
    for (int idx = tid; idx < FDIM * FDIM; idx += 256) {
        int k = idx >> 7, c = idx & 127;
        Wt[c * FDIM + k] = f2bf(W[idx]);
    }
    if (b == 0 && tid < 64) hsz[tid] = 0u;  // zeros row (row N of hs)
}

// ---------------- single-pass atomic-free scatter: private (bucket, block) segments ----------------
// pairs[b*CAP + blk*CAPB + slot] = (local_row << 24) | col  (slot via LDS atomic only)
// clocal[b*CAP + blk*CAPB + slot] = col & 255
// cnt arrays dense: rcnt[b*NBLK + blk] (coalesced read in sorter). ZERO global atomics.

__global__ __launch_bounds__(256) void k_scatter(const int* __restrict__ row, const int* __restrict__ col,
                                                 unsigned int* __restrict__ pairs,
                                                 unsigned char* __restrict__ clocal,
                                                 int* __restrict__ rcnt, int* __restrict__ ccnt,
                                                 int nE, int nb) {
    __shared__ int rh[MAXB];
    __shared__ int ch[MAXB];
    const int tid = threadIdx.x;
    const int blk = blockIdx.x;
    const int cpb = (nE + NBLK - 1) / NBLK;
    const int e0 = blk * cpb;
    int e1 = e0 + cpb; if (e1 > nE) e1 = nE;

    for (int i = tid; i < nb; i += 256) { rh[i] = 0; ch[i] = 0; }
    __syncthreads();
    for (int e = e0 + tid; e < e1; e += 256) {
        int r = row[e];
        int c = col[e];
        int rb = r >> 8, cb = c >> 8;
        int s = atomicAdd(&rh[rb], 1); if (s > CAPB - 1) s = CAPB - 1;  // safety clamp
        pairs[(size_t)rb * CAP + blk * CAPB + s] = ((unsigned int)(r & 255) << 24) | (unsigned int)c;
        int q = atomicAdd(&ch[cb], 1); if (q > CAPB - 1) q = CAPB - 1;
        clocal[(size_t)cb * CAP + blk * CAPB + q] = (unsigned char)(c & 255);
    }
    __syncthreads();
    for (int i = tid; i < nb; i += 256) {
        rcnt[(size_t)i * NBLK + blk] = rh[i] < CAPB ? rh[i] : CAPB;
        ccnt[(size_t)i * NBLK + blk] = ch[i] < CAPB ? ch[i] : CAPB;
    }
}

// ---------------- fused sort + dinv: 1 block/bucket, 512 threads = 1 thread per segment ----------------
// Thread t caches its 128B pairs-segment in NAMED registers (static indexing) + 32B clocal seg;
// LDS hist/chist via 32-way unrolled predicated updates; scan; re-scatter FROM REGISTERS
// (pairs read exactly once). Col-bucket b covers the same node range as row-bucket b -> chist = deg.

#define RHIST(k, E) if (k < rc) atomicAdd(&hist[(E) >> 24], 1);
#define RSCAT(k, E) if (k < rc) { int pos_ = atomicAdd(&lcur[(E) >> 24], 1); \
                                  csr_col[pos_] = (int)((E) & 0x00FFFFFFu); }
#define E32(M) \
  M(0,p0.x) M(1,p0.y) M(2,p0.z) M(3,p0.w) M(4,p1.x) M(5,p1.y) M(6,p1.z) M(7,p1.w) \
  M(8,p2.x) M(9,p2.y) M(10,p2.z) M(11,p2.w) M(12,p3.x) M(13,p3.y) M(14,p3.z) M(15,p3.w) \
  M(16,p4.x) M(17,p4.y) M(18,p4.z) M(19,p4.w) M(20,p5.x) M(21,p5.y) M(22,p5.z) M(23,p5.w) \
  M(24,p6.x) M(25,p6.y) M(26,p6.z) M(27,p6.w) M(28,p7.x) M(29,p7.y) M(30,p7.z) M(31,p7.w)

#define CHIST(k, W, S) if (k < cc) atomicAdd(&chist[((W) >> (S)) & 255], 1);
#define C32(M) \
  M(0,cv0.x,0) M(1,cv0.x,8) M(2,cv0.x,16) M(3,cv0.x,24) \
  M(4,cv0.y,0) M(5,cv0.y,8) M(6,cv0.y,16) M(7,cv0.y,24) \
  M(8,cv0.z,0) M(9,cv0.z,8) M(10,cv0.z,16) M(11,cv0.z,24) \
  M(12,cv0.w,0) M(13,cv0.w,8) M(14,cv0.w,16) M(15,cv0.w,24) \
  M(16,cv1.x,0) M(17,cv1.x,8) M(18,cv1.x,16) M(19,cv1.x,24) \
  M(20,cv1.y,0) M(21,cv1.y,8) M(22,cv1.y,16) M(23,cv1.y,24) \
  M(24,cv1.z,0) M(25,cv1.z,8) M(26,cv1.z,16) M(27,cv1.z,24) \
  M(28,cv1.w,0) M(29,cv1.w,8) M(30,cv1.w,16) M(31,cv1.w,24)

__global__ __launch_bounds__(512) void k_sortdinv(const int* __restrict__ rcnt, const int* __restrict__ ccnt,
                                                  const unsigned int* __restrict__ pairs,
                                                  const unsigned char* __restrict__ clocal,
                                                  uint2* __restrict__ rse, float* __restrict__ dinv,
                                                  int* __restrict__ csr_col, int n, int nb) {
    __shared__ int chist[RPB];
    __shared__ int hist[RPB];
    __shared__ int scan[RPB];
    __shared__ int lcur[RPB];
    const int b = blockIdx.x;
    const int tid = threadIdx.x;   // 0..511 = segment id (one former scatter block each)
    const int row0 = b * RPB;

    if (tid < RPB) { hist[tid] = 0; chist[tid] = 0; }
    __syncthreads();

    const int rc = rcnt[(size_t)b * NBLK + tid];   // coalesced
    const int cc = ccnt[(size_t)b * NBLK + tid];
    const uint4* ps = (const uint4*)&pairs[(size_t)b * CAP + tid * CAPB];
    uint4 p0 = ps[0], p1 = ps[1], p2 = ps[2], p3 = ps[3],
          p4 = ps[4], p5 = ps[5], p6 = ps[6], p7 = ps[7];
    const uint4* cs = (const uint4*)&clocal[(size_t)b * CAP + tid * CAPB];
    uint4 cv0 = cs[0], cv1 = cs[1];

    E32(RHIST)
    C32(CHIST)
    __syncthreads();

    if (tid < RPB) scan[tid] = hist[tid];
    __syncthreads();
    for (int off = 1; off < RPB; off <<= 1) {
        int t = (tid < RPB && tid >= off) ? scan[tid - off] : 0;
        __syncthreads();
        if (tid < RPB) scan[tid] += t;
        __syncthreads();
    }
    if (tid < RPB) {
        int ex = b * CAP + scan[tid] - hist[tid];
        lcur[tid] = ex;
        int r = row0 + tid;
        if (r < n) {
            rse[r] = make_uint2((unsigned int)ex, (unsigned int)(ex + hist[tid]));
            dinv[r] = rsqrtf((float)chist[tid] + 1.0f);
        }
    }
    __syncthreads();

    E32(RSCAT)
}

// ---------------- MFMA GEMM: hs[r][c] = bf16((A[r][:] @ W[:,c] + bias[c]) * dinv[r]) ----------------
// A: N x 128 row-major, bf16 (af32=0) or fp32 (af32=1, converted in staging).
// Wt: 128 x 128 bf16, Wt[n][k]. Output packed bf16 (2/uint).
// 128 rows/block, 4 waves in 2x2, each wave 64x64 via 4x4 16x16x32 tiles; K staged in 2 halves.

#define KH 64            // K half
#define LPAD 72          // LDS row stride in shorts (64 + 8 pad; 2-way bank alias = free)

__global__ __launch_bounds__(256) void k_gemm_mfma(const void* __restrict__ Ain,
                                                   const unsigned short* __restrict__ Wt,
                                                   const float* __restrict__ bias,
                                                   const float* __restrict__ dinv,
                                                   unsigned int* __restrict__ outp, int n, int af32) {
    __shared__ unsigned short sA[128][LPAD];
    __shared__ unsigned short sW[128][LPAD];

    const unsigned short* A = (const unsigned short*)Ain;
    const float* Af = (const float*)Ain;

    const int tid = threadIdx.x;
    const int row0 = blockIdx.x * 128;
    const int wid = tid >> 6;
    const int lane = tid & 63;
    const int quad = lane >> 4;
    const int lq = lane & 15;
    const int wm = wid & 1;        // row half
    const int wn = wid >> 1;       // col half

    floatx4 acc[4][4];
#pragma unroll
    for (int i = 0; i < 4; i++)
#pragma unroll
        for (int j = 0; j < 4; j++) acc[i][j] = (floatx4){0.f, 0.f, 0.f, 0.f};

    for (int kh = 0; kh < 2; kh++) {
        if (kh) __syncthreads();
        // stage A rows [row0,row0+128) cols [kh*64, +64), and Wt rows (all n) same k window
#pragma unroll
        for (int it = 0; it < 4; it++) {
            int f = tid + it * 256;          // 0..1023
            int r = f >> 3;                  // 0..127
            int c8 = (f & 7) * 8;            // 0..56
            int gr = row0 + r;
            if (af32) {
                float4 v0 = make_float4(0.f, 0.f, 0.f, 0.f);
                float4 v1 = make_float4(0.f, 0.f, 0.f, 0.f);
                if (gr < n) {
                    v0 = *(const float4*)&Af[(size_t)gr * FDIM + kh * KH + c8];
                    v1 = *(const float4*)&Af[(size_t)gr * FDIM + kh * KH + c8 + 4];
                }
                uint4 p;
                p.x = cvtpk(v0.x, v0.y);
                p.y = cvtpk(v0.z, v0.w);
                p.z = cvtpk(v1.x, v1.y);
                p.w = cvtpk(v1.z, v1.w);
                *(uint4*)&sA[r][c8] = p;
            } else {
                uint4 v = make_uint4(0u, 0u, 0u, 0u);
                if (gr < n) v = *(const uint4*)&A[(size_t)gr * FDIM + kh * KH + c8];
                *(uint4*)&sA[r][c8] = v;
            }
            uint4 wv = *(const uint4*)&Wt[(size_t)r * FDIM + kh * KH + c8];
            *(uint4*)&sW[r][c8] = wv;
        }
        __syncthreads();

#pragma unroll
        for (int kt = 0; kt < 2; kt++) {
            const int k0 = kt * 32 + quad * 8;
            short8 af[4], bf[4];
#pragma unroll
            for (int mt = 0; mt < 4; mt++)
                af[mt] = *(const short8*)&sA[wm * 64 + mt * 16 + lq][k0];
#pragma unroll
            for (int nt = 0; nt < 4; nt++)
                bf[nt] = *(const short8*)&sW[wn * 64 + nt * 16 + lq][k0];
#pragma unroll
            for (int mt = 0; mt < 4; mt++)
#pragma unroll
                for (int nt = 0; nt < 4; nt++)
                    acc[mt][nt] = __builtin_amdgcn_mfma_f32_16x16x32_bf16(af[mt], bf[nt], acc[mt][nt], 0, 0, 0);
        }
    }

    // epilogue: D row = quad*4+reg, col = lq (per 16x16 tile)
    float bv[4];
#pragma unroll
    for (int nt = 0; nt < 4; nt++) bv[nt] = bias[wn * 64 + nt * 16 + lq];

#pragma unroll
    for (int mt = 0; mt < 4; mt++) {
#pragma unroll
        for (int r = 0; r < 4; r++) {
            int grow = row0 + wm * 64 + mt * 16 + quad * 4 + r;
            float di = (grow < n) ? dinv[grow] : 0.f;
#pragma unroll
            for (int nt = 0; nt < 4; nt++) {
                float v = (acc[mt][nt][r] + bv[nt]) * di;
                float pv = __shfl_xor(v, 1, 64);
                if (!(lq & 1) && grow < n) {
                    int col = wn * 64 + nt * 16 + lq;
                    outp[(size_t)grow * 64 + (col >> 1)] =
                        (unsigned int)f2bf(v) | ((unsigned int)f2bf(pv) << 16);
                }
            }
        }
    }
}

// ---------------- Aggregation: out[i] = dinv[i]*(hs[i] + sum_{e in row i} hs[col[e]]) ----------------
// hs packed bf16, row n = zeros (gather target for padding lanes).
// Each global_load_dwordx4 fetches one full edge row slice (16 lanes x 16B = 256B row per quad);
// 8-edge granularity (2 loads/iter): padding waste <= 7 edges, avg ~3.5.
// Accumulator: 8 floats/lane = features lq*8..+7; cross-quad shfl_xor reduction once per node.

#define UACC(U) { float p_, q_; \
    bf2f(U.x, p_, q_); acc0 += p_; acc1 += q_; \
    bf2f(U.y, p_, q_); acc2 += p_; acc3 += q_; \
    bf2f(U.z, p_, q_); acc4 += p_; acc5 += q_; \
    bf2f(U.w, p_, q_); acc6 += p_; acc7 += q_; }

__global__ __launch_bounds__(256) void k_agg(const unsigned int* __restrict__ hs,
                                             const uint2* __restrict__ rse,
                                             const int* __restrict__ csr_col, const float* __restrict__ dinv,
                                             void* __restrict__ out, int n, int relu, int lsm, int obf) {
    int w = (blockIdx.x * 256 + threadIdx.x) >> 6;
    int lane = threadIdx.x & 63;
    if (w >= n) return;
    const int quad = lane >> 4;   // 0..3
    const int lq = lane & 15;     // features lq*8 .. lq*8+7 (uints lq*4 .. lq*4+3)

    const uint2 se = rse[w];
    int e = (int)se.x;
    const int end = (int)se.y;
    const float di = dinv[w];

    // init acc with self row (quad 0 only; other quads contribute 0, fixed by cross-quad reduce)
    uint4 sv = make_uint4(0u, 0u, 0u, 0u);
    if (quad == 0) sv = *(const uint4*)&hs[(size_t)w * 64 + lq * 4];
    float acc0, acc1, acc2, acc3, acc4, acc5, acc6, acc7;
    bf2f(sv.x, acc0, acc1);
    bf2f(sv.y, acc2, acc3);
    bf2f(sv.z, acc4, acc5);
    bf2f(sv.w, acc6, acc7);

    const int zrow = n;  // zeros row

    while (e < end) {
        int cnt = end - e;
        if (cnt > 64) cnt = 64;
        // lanes >= cnt hold zrow -> padding gathers read the zero row (L2-hot single line)
        int jv = (e + lane < end) ? csr_col[e + lane] : zrow;
        int nb8 = (cnt + 7) >> 3;
        for (int t = 0; t < nb8; t++) {
            int i0 = t * 8 + quad;
            int j0 = __shfl(jv, i0, 64);
            int j1 = __shfl(jv, i0 + 4, 64);
            uint4 u0 = *(const uint4*)&hs[(size_t)j0 * 64 + lq * 4];
            uint4 u1 = *(const uint4*)&hs[(size_t)j1 * 64 + lq * 4];
            UACC(u0)
            UACC(u1)
        }
        e += cnt;
    }

    // cross-quad reduction: lanes {lq, lq+16, lq+32, lq+48} hold partials of same features
    acc0 += __shfl_xor(acc0, 16, 64); acc0 += __shfl_xor(acc0, 32, 64);
    acc1 += __shfl_xor(acc1, 16, 64); acc1 += __shfl_xor(acc1, 32, 64);
    acc2 += __shfl_xor(acc2, 16, 64); acc2 += __shfl_xor(acc2, 32, 64);
    acc3 += __shfl_xor(acc3, 16, 64); acc3 += __shfl_xor(acc3, 32, 64);
    acc4 += __shfl_xor(acc4, 16, 64); acc4 += __shfl_xor(acc4, 32, 64);
    acc5 += __shfl_xor(acc5, 16, 64); acc5 += __shfl_xor(acc5, 32, 64);
    acc6 += __shfl_xor(acc6, 16, 64); acc6 += __shfl_xor(acc6, 32, 64);
    acc7 += __shfl_xor(acc7, 16, 64); acc7 += __shfl_xor(acc7, 32, 64);

    acc0 *= di; acc1 *= di; acc2 *= di; acc3 *= di;
    acc4 *= di; acc5 *= di; acc6 *= di; acc7 *= di;
    if (relu) {
        acc0 = fmaxf(acc0, 0.f); acc1 = fmaxf(acc1, 0.f);
        acc2 = fmaxf(acc2, 0.f); acc3 = fmaxf(acc3, 0.f);
        acc4 = fmaxf(acc4, 0.f); acc5 = fmaxf(acc5, 0.f);
        acc6 = fmaxf(acc6, 0.f); acc7 = fmaxf(acc7, 0.f);
    }
    if (lsm) {
        // features live across lq (0..15); quads hold identical copies -> reduce over lq only
        float m = fmaxf(fmaxf(fmaxf(acc0, acc1), fmaxf(acc2, acc3)),
                        fmaxf(fmaxf(acc4, acc5), fmaxf(acc6, acc7)));
#pragma unroll
        for (int off = 1; off < 16; off <<= 1) m = fmaxf(m, __shfl_xor(m, off, 64));
        float s = ((expf(acc0 - m) + expf(acc1 - m)) + (expf(acc2 - m) + expf(acc3 - m))) +
                  ((expf(acc4 - m) + expf(acc5 - m)) + (expf(acc6 - m) + expf(acc7 - m)));
#pragma unroll
        for (int off = 1; off < 16; off <<= 1) s += __shfl_xor(s, off, 64);
        float lg = m + logf(s);
        acc0 -= lg; acc1 -= lg; acc2 -= lg; acc3 -= lg;
        acc4 -= lg; acc5 -= lg; acc6 -= lg; acc7 -= lg;
    }
    if (obf) {
        if (quad == 0) {
            uint4 o;
            o.x = (unsigned int)f2bf(acc0) | ((unsigned int)f2bf(acc1) << 16);
            o.y = (unsigned int)f2bf(acc2) | ((unsigned int)f2bf(acc3) << 16);
            o.z = (unsigned int)f2bf(acc4) | ((unsigned int)f2bf(acc5) << 16);
            o.w = (unsigned int)f2bf(acc6) | ((unsigned int)f2bf(acc7) << 16);
            *(uint4*)((unsigned int*)out + (size_t)w * 64 + lq * 4) = o;
        }
    } else {
        // fp32: quad 0 writes features lq*8..+3, quad 1 writes lq*8+4..+7 (contiguous 512B/row)
        if (quad < 2) {
            float4 o = quad ? make_float4(acc4, acc5, acc6, acc7)
                            : make_float4(acc0, acc1, acc2, acc3);
            *(float4*)((float*)out + (size_t)w * 128 + lq * 8 + quad * 4) = o;
        }
    }
}

// ---------------- launch ----------------

extern "C" void kernel_launch(void* const* d_in, const int* in_sizes, int n_in,
                              void* d_out, int out_size, void* d_ws, size_t ws_size,
                              hipStream_t stream) {
    const float* x  = (const float*)d_in[0];
    const float* W0 = (const float*)d_in[1];
    const float* b0 = (const float*)d_in[2];
    const float* W1 = (const float*)d_in[3];
    const float* b1 = (const float*)d_in[4];
    const int* row  = (const int*)d_in[5];
    const int* col  = (const int*)d_in[6];
    float* out = (float*)d_out;

    const int N = in_sizes[0] / FDIM;
    const int E = in_sizes[5];
    const int NB = (N + RPB - 1) / RPB;  // buckets (391 for N=100000)

    char* w = (char*)d_ws;
    size_t off = 0;
    auto alloc = [&](size_t bytes) {
        char* p = w + off;
        off += (bytes + 255) & ~(size_t)255;
        return p;
    };
    int* rcnt    = (int*)alloc((size_t)NB * NBLK * 4);
    int* ccnt    = (int*)alloc((size_t)NB * NBLK * 4);
    float* dinv  = (float*)alloc((size_t)N * 4);
    uint2* rse   = (uint2*)alloc((size_t)N * 8);
    int* csr_col = (int*)alloc((size_t)NB * CAP * 4);   // bucket-padded CSR cols
    unsigned short* W0t = (unsigned short*)alloc((size_t)FDIM * FDIM * 2);
    unsigned short* W1t = (unsigned short*)alloc((size_t)FDIM * FDIM * 2);
    unsigned int* hs = (unsigned int*)alloc((size_t)(N + 1) * 64 * 4);  // packed bf16 hs + zero row
    // Union region: pairs+clocal (CSR build) -> hb (agg0 output, consumed by gemm1).
    // pairs/clocal consumed by k_sortdinv, which completes (stream order) before k_agg writes hb.
    size_t pairsSz = (size_t)NB * CAP * 4;
    size_t clocSz  = (size_t)NB * CAP;
    size_t uniSz   = pairsSz + clocSz + 512;
    size_t hbSz    = (size_t)N * 64 * 4;
    char* uni = (char*)alloc(uniSz > hbSz ? uniSz : hbSz);
    unsigned int* pairs = (unsigned int*)uni;
    unsigned char* clocal = (unsigned char*)(uni + pairsSz);
    unsigned int* hb = (unsigned int*)uni;   // bf16-packed h (layer-0 output)

    const int gW = (N * 64 + 255) / 256;   // wave-per-node grid
    const int gG = (N + 127) / 128;        // mfma-gemm grid

    // init (W->bf16^T + zrow), atomic-free private-segment scatter, register-cached sort+dinv
    k_init<<<2, 256, 0, stream>>>(hs + (size_t)N * 64, W0, W1, W0t, W1t);
    k_scatter<<<NBLK, 256, 0, stream>>>(row, col, pairs, clocal, rcnt, ccnt, E, NB);
    k_sortdinv<<<NB, 512, 0, stream>>>(rcnt, ccnt, pairs, clocal, rse, dinv, csr_col, N, NB);

    // layer 0: hs0 = bf16((x@W0 + b0)*dinv) (fp32 A, converted in staging); agg(+relu) -> hb
    k_gemm_mfma<<<gG, 256, 0, stream>>>((const void*)x, W0t, b0, dinv, hs, N, 1);
    k_agg<<<gW, 256, 0, stream>>>(hs, rse, csr_col, dinv, hb, N, 1, 0, 1);

    // layer 1: hs1 = bf16((h@W1 + b1)*dinv) ; agg(+log_softmax) -> d_out (fp32)
    k_gemm_mfma<<<gG, 256, 0, stream>>>((const void*)hb, W1t, b1, dinv, hs, N, 0);
    k_agg<<<gW, 256, 0, stream>>>(hs, rse, csr_col, dinv, out, N, 0, 1, 0);
}

// Round 9
// 346.828 us; speedup vs baseline: 1.0291x; 1.0291x over previous
//
#include <hip/hip_runtime.h>
#include <math.h>

#define FDIM 128
#define RPB 256      // rows per bucket (bucket = id >> 8)
#define BSTRIDE 32   // ints per counter (128 B) — one cache line per counter
#define NBLK 512     // blocks in scatter multisplit
#define MAXB 512     // max buckets (N <= 131072)
#define NSUB 8       // per-XCD sub-segments per bucket (blockIdx.x & 7 ~ XCD id)
#define SCAP 1024    // slots per (bucket, sub): mean 512, +22 sigma
#define CAP (NSUB * SCAP)   // 8192 slots per bucket

typedef __attribute__((ext_vector_type(8))) short short8;   // 8 bf16 (4 VGPRs)
typedef __attribute__((ext_vector_type(4))) float floatx4;  // 4 fp32 acc

static __device__ __forceinline__ unsigned short f2bf(float f) {
    unsigned int u = __float_as_uint(f);
    u = (u + 0x7fff + ((u >> 16) & 1)) >> 16;   // round-to-nearest-even
    return (unsigned short)u;
}

static __device__ __forceinline__ unsigned int cvtpk(float a, float b) {
    unsigned int r;
    asm("v_cvt_pk_bf16_f32 %0, %1, %2" : "=v"(r) : "v"(a), "v"(b));
    return r;
}

static __device__ __forceinline__ void bf2f(unsigned int u, float& a, float& b) {
    a = __uint_as_float(u << 16);
    b = __uint_as_float(u & 0xffff0000u);
}

// ---------------- fused init: zero counters, zrow, dinv[N]; convert W ----------------

__global__ __launch_bounds__(256) void k_init(int* rbCnt, int* cbCnt, int nb, unsigned int* hsz,
                                              float* dinvN,
                                              const float* __restrict__ W0, const float* __restrict__ W1,
                                              unsigned short* __restrict__ W0t, unsigned short* __restrict__ W1t) {
    const int b = blockIdx.x;
    const int tid = threadIdx.x;
    if (b >= 2) {
        int i0 = (b - 2) * 256 + tid;
        int tot = nb * NSUB;
        for (int i = i0; i < tot; i += (gridDim.x - 2) * 256) {
            rbCnt[(size_t)i * BSTRIDE] = 0;
            cbCnt[(size_t)i * BSTRIDE] = 0;
        }
        if (b == 2 && tid < 64) hsz[tid] = 0u;  // zeros row (row N of hs)
        if (b == 2 && tid == 64) *dinvN = 0.0f; // dinv[N] = 0 (padding-gather guard)
    } else {
        const float* W = (b == 0) ? W0 : W1;
        unsigned short* Wt = (b == 0) ? W0t : W1t;
        for (int idx = tid; idx < FDIM * FDIM; idx += 256) {
            int k = idx >> 7, c = idx & 127;
            Wt[c * FDIM + k] = f2bf(W[idx]);
        }
    }
}

// ---------------- GEMM body (device fn; shared by fused + standalone kernels) ----------------
// hs[r][c] = bf16((A[r][:]@W[:,c] + bias[c]) * (scaled ? dinv[r] : 1))
// A bf16 (af32=0) or fp32 (af32=1, converted during staging). 128 rows/block, 4 waves 2x2.

#define KH 64
#define LPAD 72          // LDS row stride in shorts (64 + 8 pad; 2-way bank alias = free)
#define GSMEM (2 * 128 * LPAD * 2)   // 36864 bytes

static __device__ __forceinline__ void gemm_body(char* smem, const void* __restrict__ Ain,
                                                 const unsigned short* __restrict__ Wt,
                                                 const float* __restrict__ bias,
                                                 const float* __restrict__ dinv,
                                                 unsigned int* __restrict__ outp, int n,
                                                 int af32, int scaled, int blk) {
    unsigned short (*sA)[LPAD] = (unsigned short(*)[LPAD])smem;
    unsigned short (*sW)[LPAD] = (unsigned short(*)[LPAD])(smem + 128 * LPAD * 2);

    const unsigned short* A = (const unsigned short*)Ain;
    const float* Af = (const float*)Ain;

    const int tid = threadIdx.x;
    const int row0 = blk * 128;
    const int wid = tid >> 6;
    const int lane = tid & 63;
    const int quad = lane >> 4;
    const int lq = lane & 15;
    const int wm = wid & 1;
    const int wn = wid >> 1;

    floatx4 acc[4][4];
#pragma unroll
    for (int i = 0; i < 4; i++)
#pragma unroll
        for (int j = 0; j < 4; j++) acc[i][j] = (floatx4){0.f, 0.f, 0.f, 0.f};

    for (int kh = 0; kh < 2; kh++) {
        if (kh) __syncthreads();
#pragma unroll
        for (int it = 0; it < 4; it++) {
            int f = tid + it * 256;
            int r = f >> 3;
            int c8 = (f & 7) * 8;
            int gr = row0 + r;
            if (af32) {
                float4 v0 = make_float4(0.f, 0.f, 0.f, 0.f);
                float4 v1 = make_float4(0.f, 0.f, 0.f, 0.f);
                if (gr < n) {
                    v0 = *(const float4*)&Af[(size_t)gr * FDIM + kh * KH + c8];
                    v1 = *(const float4*)&Af[(size_t)gr * FDIM + kh * KH + c8 + 4];
                }
                uint4 p;
                p.x = cvtpk(v0.x, v0.y);
                p.y = cvtpk(v0.z, v0.w);
                p.z = cvtpk(v1.x, v1.y);
                p.w = cvtpk(v1.z, v1.w);
                *(uint4*)&sA[r][c8] = p;
            } else {
                uint4 v = make_uint4(0u, 0u, 0u, 0u);
                if (gr < n) v = *(const uint4*)&A[(size_t)gr * FDIM + kh * KH + c8];
                *(uint4*)&sA[r][c8] = v;
            }
            uint4 wv = *(const uint4*)&Wt[(size_t)r * FDIM + kh * KH + c8];
            *(uint4*)&sW[r][c8] = wv;
        }
        __syncthreads();

#pragma unroll
        for (int kt = 0; kt < 2; kt++) {
            const int k0 = kt * 32 + quad * 8;
            short8 af[4], bf[4];
#pragma unroll
            for (int mt = 0; mt < 4; mt++)
                af[mt] = *(const short8*)&sA[wm * 64 + mt * 16 + lq][k0];
#pragma unroll
            for (int nt = 0; nt < 4; nt++)
                bf[nt] = *(const short8*)&sW[wn * 64 + nt * 16 + lq][k0];
#pragma unroll
            for (int mt = 0; mt < 4; mt++)
#pragma unroll
                for (int nt = 0; nt < 4; nt++)
                    acc[mt][nt] = __builtin_amdgcn_mfma_f32_16x16x32_bf16(af[mt], bf[nt], acc[mt][nt], 0, 0, 0);
        }
    }

    float bv[4];
#pragma unroll
    for (int nt = 0; nt < 4; nt++) bv[nt] = bias[wn * 64 + nt * 16 + lq];

#pragma unroll
    for (int mt = 0; mt < 4; mt++) {
#pragma unroll
        for (int r = 0; r < 4; r++) {
            int grow = row0 + wm * 64 + mt * 16 + quad * 4 + r;
            float di = scaled ? ((grow < n) ? dinv[grow] : 0.f) : 1.0f;
#pragma unroll
            for (int nt = 0; nt < 4; nt++) {
                float v = (acc[mt][nt][r] + bv[nt]) * di;
                float pv = __shfl_xor(v, 1, 64);
                if (!(lq & 1) && grow < n) {
                    int col = wn * 64 + nt * 16 + lq;
                    outp[(size_t)grow * 64 + (col >> 1)] =
                        (unsigned int)f2bf(v) | ((unsigned int)f2bf(pv) << 16);
                }
            }
        }
    }
}

// ---------------- FUSED scatter + gemm0_raw: blocks [0,NBLK)=scatter, rest=gemm ----------------
// Scatter (round-6 proven structure): XCD-sub reservation, contiguous runs -> dense lines.
// gemm0_raw: hs_raw = bf16(x@W0 + b0), UNSCALED (dinv not yet available) -> no dependency,
// so the compute-dense gemm co-resides with the atomic-latency-bound scatter (occ 14%, VALU 1%).

__global__ __launch_bounds__(256) void k_scatter_gemm(const int* __restrict__ row, const int* __restrict__ col,
                                                      int* rbCnt, int* cbCnt,
                                                      unsigned int* __restrict__ pairs,
                                                      unsigned char* __restrict__ clocal, int nE, int nb,
                                                      const float* __restrict__ x,
                                                      const unsigned short* __restrict__ W0t,
                                                      const float* __restrict__ b0,
                                                      unsigned int* __restrict__ hs, int n) {
    __shared__ __align__(16) char smem[GSMEM];

    if (blockIdx.x >= NBLK) {
        gemm_body(smem, (const void*)x, W0t, b0, (const float*)nullptr, hs, n, 1, 0, blockIdx.x - NBLK);
        return;
    }

    int* rh    = (int*)smem;
    int* ch    = (int*)(smem + MAXB * 4);
    int* rbase = (int*)(smem + MAXB * 8);
    int* cbase = (int*)(smem + MAXB * 12);
    const int tid = threadIdx.x;
    const int sub = blockIdx.x & (NSUB - 1);
    const int cpb = (nE + NBLK - 1) / NBLK;
    const int e0 = blockIdx.x * cpb;
    int e1 = e0 + cpb; if (e1 > nE) e1 = nE;

    for (int i = tid; i < nb; i += 256) { rh[i] = 0; ch[i] = 0; }
    __syncthreads();
    for (int e = e0 + tid; e < e1; e += 256) {
        atomicAdd(&rh[row[e] >> 8], 1);
        atomicAdd(&ch[col[e] >> 8], 1);
    }
    __syncthreads();
    for (int i = tid; i < nb; i += 256) {
        rbase[i] = rh[i] ? (i * CAP + sub * SCAP +
                            atomicAdd(&rbCnt[(size_t)(i * NSUB + sub) * BSTRIDE], rh[i])) : 0;
        cbase[i] = ch[i] ? (i * CAP + sub * SCAP +
                            atomicAdd(&cbCnt[(size_t)(i * NSUB + sub) * BSTRIDE], ch[i])) : 0;
        rh[i] = 0;
        ch[i] = 0;
    }
    __syncthreads();
    const int pmax = nb * CAP - 1;
    for (int e = e0 + tid; e < e1; e += 256) {
        int r = row[e];
        int c = col[e];
        int rb = r >> 8, cb = c >> 8;
        int p = rbase[rb] + atomicAdd(&rh[rb], 1);
        if (p > pmax) p = pmax;  // memory-safety clamp (statistically unreachable)
        pairs[p] = ((unsigned int)(r & (RPB - 1)) << 24) | (unsigned int)c;
        int q = cbase[cb] + atomicAdd(&ch[cb], 1);
        if (q > pmax) q = pmax;
        clocal[q] = (unsigned char)(c & (RPB - 1));
    }
}

// ---------------- fused sort + dinv (round-6 proven): per bucket b, nodes [b*256,(b+1)*256) ----------------

__global__ __launch_bounds__(256) void k_sortdinv(const int* __restrict__ rbCnt, const int* __restrict__ cbCnt,
                                                  const unsigned int* __restrict__ pairs,
                                                  const unsigned char* __restrict__ clocal,
                                                  uint2* __restrict__ rse, float* __restrict__ dinv,
                                                  int* __restrict__ csr_col, int n, int nb) {
    __shared__ int chist[RPB];
    __shared__ int hist[RPB];
    __shared__ int scan[RPB];
    __shared__ int lcur[RPB];
    const int b = blockIdx.x;
    const int tid = threadIdx.x;
    const int row0 = b * RPB;

    hist[tid] = 0;
    chist[tid] = 0;
    __syncthreads();
#pragma unroll
    for (int s = 0; s < NSUB; s++) {
        int rc = rbCnt[(size_t)(b * NSUB + s) * BSTRIDE]; if (rc > SCAP) rc = SCAP;
        int cc = cbCnt[(size_t)(b * NSUB + s) * BSTRIDE]; if (cc > SCAP) cc = SCAP;
        const int seg0 = b * CAP + s * SCAP;
        for (int i = seg0 + tid; i < seg0 + rc; i += 256)
            atomicAdd(&hist[pairs[i] >> 24], 1);
        for (int i = seg0 + tid; i < seg0 + cc; i += 256)
            atomicAdd(&chist[(int)clocal[i]], 1);
    }
    __syncthreads();

    scan[tid] = hist[tid];
    __syncthreads();
    for (int off = 1; off < RPB; off <<= 1) {
        int t = (tid >= off) ? scan[tid - off] : 0;
        __syncthreads();
        scan[tid] += t;
        __syncthreads();
    }
    {
        int ex = b * CAP + scan[tid] - hist[tid];
        lcur[tid] = ex;
        int r = row0 + tid;
        if (r < n) {
            rse[r] = make_uint2((unsigned int)ex, (unsigned int)(ex + hist[tid]));
            dinv[r] = rsqrtf((float)chist[tid] + 1.0f);
        }
    }
    __syncthreads();

#pragma unroll
    for (int s = 0; s < NSUB; s++) {
        int rc = rbCnt[(size_t)(b * NSUB + s) * BSTRIDE]; if (rc > SCAP) rc = SCAP;
        const int seg0 = b * CAP + s * SCAP;
        for (int i = seg0 + tid; i < seg0 + rc; i += 256) {
            unsigned int u = pairs[i];
            int pos = atomicAdd(&lcur[u >> 24], 1);
            csr_col[pos] = (int)(u & 0x00FFFFFFu);
        }
    }
}

// ---------------- standalone GEMM (layer 1, dinv-scaled) ----------------

__global__ __launch_bounds__(256) void k_gemm_mfma(const void* __restrict__ Ain,
                                                   const unsigned short* __restrict__ Wt,
                                                   const float* __restrict__ bias,
                                                   const float* __restrict__ dinv,
                                                   unsigned int* __restrict__ outp, int n, int af32) {
    __shared__ __align__(16) char smem[GSMEM];
    gemm_body(smem, Ain, Wt, bias, dinv, outp, n, af32, 1, blockIdx.x);
}

// ---------------- Aggregation ----------------
// es=1 (layer 0): hs is UNSCALED; out = dinv_i*(dinv_i*h_i + sum_j dinv_j*h_j)
//   -> acc init = di*h_self; gather FMA with dj (dinv L2-resident broadcast; not on L3-BW path)
// es=0 (layer 1): hs pre-scaled; out = dinv_i*(h_i + sum h_j)  (original)

#define UACC(U) { float p_, q_; \
    bf2f(U.x, p_, q_); acc0 += p_; acc1 += q_; \
    bf2f(U.y, p_, q_); acc2 += p_; acc3 += q_; \
    bf2f(U.z, p_, q_); acc4 += p_; acc5 += q_; \
    bf2f(U.w, p_, q_); acc6 += p_; acc7 += q_; }

#define UACCD(U, DJ) { float p_, q_; \
    bf2f(U.x, p_, q_); acc0 = fmaf(p_, DJ, acc0); acc1 = fmaf(q_, DJ, acc1); \
    bf2f(U.y, p_, q_); acc2 = fmaf(p_, DJ, acc2); acc3 = fmaf(q_, DJ, acc3); \
    bf2f(U.z, p_, q_); acc4 = fmaf(p_, DJ, acc4); acc5 = fmaf(q_, DJ, acc5); \
    bf2f(U.w, p_, q_); acc6 = fmaf(p_, DJ, acc6); acc7 = fmaf(q_, DJ, acc7); }

__global__ __launch_bounds__(256) void k_agg(const unsigned int* __restrict__ hs,
                                             const uint2* __restrict__ rse,
                                             const int* __restrict__ csr_col, const float* __restrict__ dinv,
                                             void* __restrict__ out, int n, int relu, int lsm, int obf, int es) {
    int w = (blockIdx.x * 256 + threadIdx.x) >> 6;
    int lane = threadIdx.x & 63;
    if (w >= n) return;
    const int quad = lane >> 4;
    const int lq = lane & 15;

    const uint2 se = rse[w];
    int e = (int)se.x;
    const int end = (int)se.y;
    const float di = dinv[w];

    uint4 sv = make_uint4(0u, 0u, 0u, 0u);
    if (quad == 0) sv = *(const uint4*)&hs[(size_t)w * 64 + lq * 4];
    float acc0, acc1, acc2, acc3, acc4, acc5, acc6, acc7;
    bf2f(sv.x, acc0, acc1);
    bf2f(sv.y, acc2, acc3);
    bf2f(sv.z, acc4, acc5);
    bf2f(sv.w, acc6, acc7);
    if (es) {   // self term: di*h_i (so final *di gives di^2*h_i)
        acc0 *= di; acc1 *= di; acc2 *= di; acc3 *= di;
        acc4 *= di; acc5 *= di; acc6 *= di; acc7 *= di;
    }

    const int zrow = n;  // zeros row (dinv[n]=0)

    while (e < end) {
        int cnt = end - e;
        if (cnt > 64) cnt = 64;
        int jv = (e + lane < end) ? csr_col[e + lane] : zrow;
        int nb8 = (cnt + 7) >> 3;
        for (int t = 0; t < nb8; t++) {
            int i0 = t * 8 + quad;
            int j0 = __shfl(jv, i0, 64);
            int j1 = __shfl(jv, i0 + 4, 64);
            uint4 u0 = *(const uint4*)&hs[(size_t)j0 * 64 + lq * 4];
            uint4 u1 = *(const uint4*)&hs[(size_t)j1 * 64 + lq * 4];
            if (es) {
                float dj0 = dinv[j0];
                float dj1 = dinv[j1];
                UACCD(u0, dj0)
                UACCD(u1, dj1)
            } else {
                UACC(u0)
                UACC(u1)
            }
        }
        e += cnt;
    }

    acc0 += __shfl_xor(acc0, 16, 64); acc0 += __shfl_xor(acc0, 32, 64);
    acc1 += __shfl_xor(acc1, 16, 64); acc1 += __shfl_xor(acc1, 32, 64);
    acc2 += __shfl_xor(acc2, 16, 64); acc2 += __shfl_xor(acc2, 32, 64);
    acc3 += __shfl_xor(acc3, 16, 64); acc3 += __shfl_xor(acc3, 32, 64);
    acc4 += __shfl_xor(acc4, 16, 64); acc4 += __shfl_xor(acc4, 32, 64);
    acc5 += __shfl_xor(acc5, 16, 64); acc5 += __shfl_xor(acc5, 32, 64);
    acc6 += __shfl_xor(acc6, 16, 64); acc6 += __shfl_xor(acc6, 32, 64);
    acc7 += __shfl_xor(acc7, 16, 64); acc7 += __shfl_xor(acc7, 32, 64);

    acc0 *= di; acc1 *= di; acc2 *= di; acc3 *= di;
    acc4 *= di; acc5 *= di; acc6 *= di; acc7 *= di;
    if (relu) {
        acc0 = fmaxf(acc0, 0.f); acc1 = fmaxf(acc1, 0.f);
        acc2 = fmaxf(acc2, 0.f); acc3 = fmaxf(acc3, 0.f);
        acc4 = fmaxf(acc4, 0.f); acc5 = fmaxf(acc5, 0.f);
        acc6 = fmaxf(acc6, 0.f); acc7 = fmaxf(acc7, 0.f);
    }
    if (lsm) {
        float m = fmaxf(fmaxf(fmaxf(acc0, acc1), fmaxf(acc2, acc3)),
                        fmaxf(fmaxf(acc4, acc5), fmaxf(acc6, acc7)));
#pragma unroll
        for (int off = 1; off < 16; off <<= 1) m = fmaxf(m, __shfl_xor(m, off, 64));
        float s = ((expf(acc0 - m) + expf(acc1 - m)) + (expf(acc2 - m) + expf(acc3 - m))) +
                  ((expf(acc4 - m) + expf(acc5 - m)) + (expf(acc6 - m) + expf(acc7 - m)));
#pragma unroll
        for (int off = 1; off < 16; off <<= 1) s += __shfl_xor(s, off, 64);
        float lg = m + logf(s);
        acc0 -= lg; acc1 -= lg; acc2 -= lg; acc3 -= lg;
        acc4 -= lg; acc5 -= lg; acc6 -= lg; acc7 -= lg;
    }
    if (obf) {
        if (quad == 0) {
            uint4 o;
            o.x = (unsigned int)f2bf(acc0) | ((unsigned int)f2bf(acc1) << 16);
            o.y = (unsigned int)f2bf(acc2) | ((unsigned int)f2bf(acc3) << 16);
            o.z = (unsigned int)f2bf(acc4) | ((unsigned int)f2bf(acc5) << 16);
            o.w = (unsigned int)f2bf(acc6) | ((unsigned int)f2bf(acc7) << 16);
            *(uint4*)((unsigned int*)out + (size_t)w * 64 + lq * 4) = o;
        }
    } else {
        if (quad < 2) {
            float4 o = quad ? make_float4(acc4, acc5, acc6, acc7)
                            : make_float4(acc0, acc1, acc2, acc3);
            *(float4*)((float*)out + (size_t)w * 128 + lq * 8 + quad * 4) = o;
        }
    }
}

// ---------------- launch ----------------

extern "C" void kernel_launch(void* const* d_in, const int* in_sizes, int n_in,
                              void* d_out, int out_size, void* d_ws, size_t ws_size,
                              hipStream_t stream) {
    const float* x  = (const float*)d_in[0];
    const float* W0 = (const float*)d_in[1];
    const float* b0 = (const float*)d_in[2];
    const float* W1 = (const float*)d_in[3];
    const float* b1 = (const float*)d_in[4];
    const int* row  = (const int*)d_in[5];
    const int* col  = (const int*)d_in[6];
    float* out = (float*)d_out;

    const int N = in_sizes[0] / FDIM;
    const int E = in_sizes[5];
    const int NB = (N + RPB - 1) / RPB;  // buckets (391 for N=100000)

    char* w = (char*)d_ws;
    size_t off = 0;
    auto alloc = [&](size_t bytes) {
        char* p = w + off;
        off += (bytes + 255) & ~(size_t)255;
        return p;
    };
    int* rbCnt   = (int*)alloc((size_t)NB * NSUB * BSTRIDE * 4);
    int* cbCnt   = (int*)alloc((size_t)NB * NSUB * BSTRIDE * 4);
    float* dinv  = (float*)alloc((size_t)(N + 1) * 4);   // +1: dinv[N]=0 for padding rows
    uint2* rse   = (uint2*)alloc((size_t)N * 8);
    int* csr_col = (int*)alloc((size_t)NB * CAP * 4);
    unsigned short* W0t = (unsigned short*)alloc((size_t)FDIM * FDIM * 2);
    unsigned short* W1t = (unsigned short*)alloc((size_t)FDIM * FDIM * 2);
    unsigned int* hs = (unsigned int*)alloc((size_t)(N + 1) * 64 * 4);  // packed bf16 hs + zero row
    // Union region: pairs+clocal (CSR build) -> hb (agg0 output, consumed by gemm1).
    size_t pairsSz = (size_t)NB * CAP * 4;
    size_t clocSz  = (size_t)NB * CAP;
    size_t uniSz   = pairsSz + clocSz + 512;
    size_t hbSz    = (size_t)N * 64 * 4;
    char* uni = (char*)alloc(uniSz > hbSz ? uniSz : hbSz);
    unsigned int* pairs = (unsigned int*)uni;
    unsigned char* clocal = (unsigned char*)(uni + pairsSz);
    unsigned int* hb = (unsigned int*)uni;   // bf16-packed h (layer-0 output)

    const int gW = (N * 64 + 255) / 256;   // wave-per-node grid
    const int gG = (N + 127) / 128;        // mfma-gemm grid

    // init, then FUSED [scatter || gemm0_raw], then sort+dinv
    k_init<<<16, 256, 0, stream>>>(rbCnt, cbCnt, NB, hs + (size_t)N * 64, dinv + N, W0, W1, W0t, W1t);
    k_scatter_gemm<<<NBLK + gG, 256, 0, stream>>>(row, col, rbCnt, cbCnt, pairs, clocal, E, NB,
                                                  x, W0t, b0, hs, N);
    k_sortdinv<<<NB, 256, 0, stream>>>(rbCnt, cbCnt, pairs, clocal, rse, dinv, csr_col, N, NB);

    // layer 0 agg: per-edge dinv[j] scaling (hs is raw) ; +relu -> hb (packed bf16)
    k_agg<<<gW, 256, 0, stream>>>(hs, rse, csr_col, dinv, hb, N, 1, 0, 1, 1);

    // layer 1: hs1 = bf16((hb@W1 + b1)*dinv) ; agg(+log_softmax) -> out (fp32)
    k_gemm_mfma<<<gG, 256, 0, stream>>>((const void*)hb, W1t, b1, dinv, hs, N, 0);
    k_agg<<<gW, 256, 0, stream>>>(hs, rse, csr_col, dinv, out, N, 0, 1, 0, 0);
}

// Round 10
// 337.995 us; speedup vs baseline: 1.0560x; 1.0261x over previous
//
#include <hip/hip_runtime.h>
#include <math.h>

#define FDIM 128
#define RPB 256      // rows per bucket (bucket = id >> 8)
#define BSTRIDE 32   // ints per counter (128 B) — one cache line per counter
#define NBLK 512     // blocks in scatter multisplit
#define MAXB 512     // max buckets (N <= 131072)
#define NSUB 8       // per-XCD sub-segments per bucket (blockIdx.x & 7 ~ XCD id)
#define SCAP 1024    // slots per (bucket, sub): mean 512, +22 sigma
#define CAP (NSUB * SCAP)   // 8192 slots per bucket

typedef __attribute__((ext_vector_type(8))) short short8;   // 8 bf16 (4 VGPRs)
typedef __attribute__((ext_vector_type(4))) float floatx4;  // 4 fp32 acc

static __device__ __forceinline__ unsigned short f2bf(float f) {
    unsigned int u = __float_as_uint(f);
    u = (u + 0x7fff + ((u >> 16) & 1)) >> 16;   // round-to-nearest-even
    return (unsigned short)u;
}

static __device__ __forceinline__ unsigned int cvtpk(float a, float b) {
    unsigned int r;
    asm("v_cvt_pk_bf16_f32 %0, %1, %2" : "=v"(r) : "v"(a), "v"(b));
    return r;
}

static __device__ __forceinline__ void bf2f(unsigned int u, float& a, float& b) {
    a = __uint_as_float(u << 16);
    b = __uint_as_float(u & 0xffff0000u);
}

// ---------------- fused init: zero counters, zrow, dinv[N]; convert W ----------------

__global__ __launch_bounds__(256) void k_init(int* rbCnt, int* cbCnt, int nb, unsigned int* hsz,
                                              float* dinvN,
                                              const float* __restrict__ W0, const float* __restrict__ W1,
                                              unsigned short* __restrict__ W0t, unsigned short* __restrict__ W1t) {
    const int b = blockIdx.x;
    const int tid = threadIdx.x;
    if (b >= 2) {
        int i0 = (b - 2) * 256 + tid;
        int tot = nb * NSUB;
        for (int i = i0; i < tot; i += (gridDim.x - 2) * 256) {
            rbCnt[(size_t)i * BSTRIDE] = 0;
            cbCnt[(size_t)i * BSTRIDE] = 0;
        }
        if (b == 2 && tid < 64) hsz[tid] = 0u;  // zeros row (row N of hs)
        if (b == 2 && tid == 64) *dinvN = 0.0f; // dinv[N] = 0 (padding-gather guard)
    } else {
        const float* W = (b == 0) ? W0 : W1;
        unsigned short* Wt = (b == 0) ? W0t : W1t;
        for (int idx = tid; idx < FDIM * FDIM; idx += 256) {
            int k = idx >> 7, c = idx & 127;
            Wt[c * FDIM + k] = f2bf(W[idx]);
        }
    }
}

// ---------------- GEMM body (device fn; shared by fused + standalone kernels) ----------------

#define KH 64
#define LPAD 72          // LDS row stride in shorts (64 + 8 pad; 2-way bank alias = free)
#define GSMEM (2 * 128 * LPAD * 2)   // 36864 bytes

static __device__ __forceinline__ void gemm_body(char* smem, const void* __restrict__ Ain,
                                                 const unsigned short* __restrict__ Wt,
                                                 const float* __restrict__ bias,
                                                 const float* __restrict__ dinv,
                                                 unsigned int* __restrict__ outp, int n,
                                                 int af32, int scaled, int blk) {
    unsigned short (*sA)[LPAD] = (unsigned short(*)[LPAD])smem;
    unsigned short (*sW)[LPAD] = (unsigned short(*)[LPAD])(smem + 128 * LPAD * 2);

    const unsigned short* A = (const unsigned short*)Ain;
    const float* Af = (const float*)Ain;

    const int tid = threadIdx.x;
    const int row0 = blk * 128;
    const int wid = tid >> 6;
    const int lane = tid & 63;
    const int quad = lane >> 4;
    const int lq = lane & 15;
    const int wm = wid & 1;
    const int wn = wid >> 1;

    floatx4 acc[4][4];
#pragma unroll
    for (int i = 0; i < 4; i++)
#pragma unroll
        for (int j = 0; j < 4; j++) acc[i][j] = (floatx4){0.f, 0.f, 0.f, 0.f};

    for (int kh = 0; kh < 2; kh++) {
        if (kh) __syncthreads();
#pragma unroll
        for (int it = 0; it < 4; it++) {
            int f = tid + it * 256;
            int r = f >> 3;
            int c8 = (f & 7) * 8;
            int gr = row0 + r;
            if (af32) {
                float4 v0 = make_float4(0.f, 0.f, 0.f, 0.f);
                float4 v1 = make_float4(0.f, 0.f, 0.f, 0.f);
                if (gr < n) {
                    v0 = *(const float4*)&Af[(size_t)gr * FDIM + kh * KH + c8];
                    v1 = *(const float4*)&Af[(size_t)gr * FDIM + kh * KH + c8 + 4];
                }
                uint4 p;
                p.x = cvtpk(v0.x, v0.y);
                p.y = cvtpk(v0.z, v0.w);
                p.z = cvtpk(v1.x, v1.y);
                p.w = cvtpk(v1.z, v1.w);
                *(uint4*)&sA[r][c8] = p;
            } else {
                uint4 v = make_uint4(0u, 0u, 0u, 0u);
                if (gr < n) v = *(const uint4*)&A[(size_t)gr * FDIM + kh * KH + c8];
                *(uint4*)&sA[r][c8] = v;
            }
            uint4 wv = *(const uint4*)&Wt[(size_t)r * FDIM + kh * KH + c8];
            *(uint4*)&sW[r][c8] = wv;
        }
        __syncthreads();

#pragma unroll
        for (int kt = 0; kt < 2; kt++) {
            const int k0 = kt * 32 + quad * 8;
            short8 af[4], bf[4];
#pragma unroll
            for (int mt = 0; mt < 4; mt++)
                af[mt] = *(const short8*)&sA[wm * 64 + mt * 16 + lq][k0];
#pragma unroll
            for (int nt = 0; nt < 4; nt++)
                bf[nt] = *(const short8*)&sW[wn * 64 + nt * 16 + lq][k0];
#pragma unroll
            for (int mt = 0; mt < 4; mt++)
#pragma unroll
                for (int nt = 0; nt < 4; nt++)
                    acc[mt][nt] = __builtin_amdgcn_mfma_f32_16x16x32_bf16(af[mt], bf[nt], acc[mt][nt], 0, 0, 0);
        }
    }

    float bv[4];
#pragma unroll
    for (int nt = 0; nt < 4; nt++) bv[nt] = bias[wn * 64 + nt * 16 + lq];

#pragma unroll
    for (int mt = 0; mt < 4; mt++) {
#pragma unroll
        for (int r = 0; r < 4; r++) {
            int grow = row0 + wm * 64 + mt * 16 + quad * 4 + r;
            float di = scaled ? ((grow < n) ? dinv[grow] : 0.f) : 1.0f;
#pragma unroll
            for (int nt = 0; nt < 4; nt++) {
                float v = (acc[mt][nt][r] + bv[nt]) * di;
                float pv = __shfl_xor(v, 1, 64);
                if (!(lq & 1) && grow < n) {
                    int col = wn * 64 + nt * 16 + lq;
                    outp[(size_t)grow * 64 + (col >> 1)] =
                        (unsigned int)f2bf(v) | ((unsigned int)f2bf(pv) << 16);
                }
            }
        }
    }
}

// ---------------- FUSED scatter + gemm0_raw (round-9 proven) ----------------

__global__ __launch_bounds__(256) void k_scatter_gemm(const int* __restrict__ row, const int* __restrict__ col,
                                                      int* rbCnt, int* cbCnt,
                                                      unsigned int* __restrict__ pairs,
                                                      unsigned char* __restrict__ clocal, int nE, int nb,
                                                      const float* __restrict__ x,
                                                      const unsigned short* __restrict__ W0t,
                                                      const float* __restrict__ b0,
                                                      unsigned int* __restrict__ hs, int n) {
    __shared__ __align__(16) char smem[GSMEM];

    if (blockIdx.x >= NBLK) {
        gemm_body(smem, (const void*)x, W0t, b0, (const float*)nullptr, hs, n, 1, 0, blockIdx.x - NBLK);
        return;
    }

    int* rh    = (int*)smem;
    int* ch    = (int*)(smem + MAXB * 4);
    int* rbase = (int*)(smem + MAXB * 8);
    int* cbase = (int*)(smem + MAXB * 12);
    const int tid = threadIdx.x;
    const int sub = blockIdx.x & (NSUB - 1);
    const int cpb = (nE + NBLK - 1) / NBLK;
    const int e0 = blockIdx.x * cpb;
    int e1 = e0 + cpb; if (e1 > nE) e1 = nE;

    for (int i = tid; i < nb; i += 256) { rh[i] = 0; ch[i] = 0; }
    __syncthreads();
    for (int e = e0 + tid; e < e1; e += 256) {
        atomicAdd(&rh[row[e] >> 8], 1);
        atomicAdd(&ch[col[e] >> 8], 1);
    }
    __syncthreads();
    for (int i = tid; i < nb; i += 256) {
        rbase[i] = rh[i] ? (i * CAP + sub * SCAP +
                            atomicAdd(&rbCnt[(size_t)(i * NSUB + sub) * BSTRIDE], rh[i])) : 0;
        cbase[i] = ch[i] ? (i * CAP + sub * SCAP +
                            atomicAdd(&cbCnt[(size_t)(i * NSUB + sub) * BSTRIDE], ch[i])) : 0;
        rh[i] = 0;
        ch[i] = 0;
    }
    __syncthreads();
    const int pmax = nb * CAP - 1;
    for (int e = e0 + tid; e < e1; e += 256) {
        int r = row[e];
        int c = col[e];
        int rb = r >> 8, cb = c >> 8;
        int p = rbase[rb] + atomicAdd(&rh[rb], 1);
        if (p > pmax) p = pmax;  // memory-safety clamp (statistically unreachable)
        pairs[p] = ((unsigned int)(r & (RPB - 1)) << 24) | (unsigned int)c;
        int q = cbase[cb] + atomicAdd(&ch[cb], 1);
        if (q > pmax) q = pmax;
        clocal[q] = (unsigned char)(c & (RPB - 1));
    }
}

// ---------------- sort + dinv, v2: 512 threads, 2 segments concurrent, uint4 loads ----------------
// Group g = tid>>8 processes sub-segments {g, g+2, g+4, g+6}; thread handles 4 consecutive
// entries per segment via one predicated uint4 (pairs) / uint (clocal) load.
// 8 waves/block (vs 4) -> 2x TLP; 4x fewer VMEM instructions. No read duplication.

__global__ __launch_bounds__(512) void k_sortdinv(const int* __restrict__ rbCnt, const int* __restrict__ cbCnt,
                                                  const unsigned int* __restrict__ pairs,
                                                  const unsigned char* __restrict__ clocal,
                                                  uint2* __restrict__ rse, float* __restrict__ dinv,
                                                  int* __restrict__ csr_col, int n, int nb) {
    __shared__ int chist[RPB];
    __shared__ int hist[RPB];
    __shared__ int scan[RPB];
    __shared__ int lcur[RPB];
    const int b = blockIdx.x;
    const int tid = threadIdx.x;
    const int grp = tid >> 8;      // 0 or 1
    const int lt = tid & 255;      // 0..255
    const int row0 = b * RPB;
    const int base4 = lt * 4;      // entry index of this thread's uint4 within a segment

    if (tid < RPB) { hist[tid] = 0; chist[tid] = 0; }
    __syncthreads();

#pragma unroll
    for (int sp = 0; sp < NSUB; sp += 2) {
        const int s = sp + grp;
        int rc = rbCnt[(size_t)(b * NSUB + s) * BSTRIDE]; if (rc > SCAP) rc = SCAP;
        int cc = cbCnt[(size_t)(b * NSUB + s) * BSTRIDE]; if (cc > SCAP) cc = SCAP;
        const unsigned int* seg = &pairs[(size_t)b * CAP + s * SCAP];
        if (base4 < rc) {
            uint4 v = *(const uint4*)&seg[base4];
            atomicAdd(&hist[v.x >> 24], 1);
            if (base4 + 1 < rc) atomicAdd(&hist[v.y >> 24], 1);
            if (base4 + 2 < rc) atomicAdd(&hist[v.z >> 24], 1);
            if (base4 + 3 < rc) atomicAdd(&hist[v.w >> 24], 1);
        }
        const unsigned int* cseg = (const unsigned int*)&clocal[(size_t)b * CAP + s * SCAP];
        if (base4 < cc) {
            unsigned int cv = cseg[lt];
            atomicAdd(&chist[cv & 255], 1);
            if (base4 + 1 < cc) atomicAdd(&chist[(cv >> 8) & 255], 1);
            if (base4 + 2 < cc) atomicAdd(&chist[(cv >> 16) & 255], 1);
            if (base4 + 3 < cc) atomicAdd(&chist[cv >> 24], 1);
        }
    }
    __syncthreads();

    if (tid < RPB) scan[tid] = hist[tid];
    __syncthreads();
    for (int off = 1; off < RPB; off <<= 1) {
        int t = (tid < RPB && tid >= off) ? scan[tid - off] : 0;
        __syncthreads();
        if (tid < RPB) scan[tid] += t;
        __syncthreads();
    }
    if (tid < RPB) {
        int ex = b * CAP + scan[tid] - hist[tid];
        lcur[tid] = ex;
        int r = row0 + tid;
        if (r < n) {
            rse[r] = make_uint2((unsigned int)ex, (unsigned int)(ex + hist[tid]));
            dinv[r] = rsqrtf((float)chist[tid] + 1.0f);
        }
    }
    __syncthreads();

#pragma unroll
    for (int sp = 0; sp < NSUB; sp += 2) {
        const int s = sp + grp;
        int rc = rbCnt[(size_t)(b * NSUB + s) * BSTRIDE]; if (rc > SCAP) rc = SCAP;
        const unsigned int* seg = &pairs[(size_t)b * CAP + s * SCAP];
        if (base4 < rc) {
            uint4 v = *(const uint4*)&seg[base4];
            int pos = atomicAdd(&lcur[v.x >> 24], 1);
            csr_col[pos] = (int)(v.x & 0x00FFFFFFu);
            if (base4 + 1 < rc) { pos = atomicAdd(&lcur[v.y >> 24], 1); csr_col[pos] = (int)(v.y & 0x00FFFFFFu); }
            if (base4 + 2 < rc) { pos = atomicAdd(&lcur[v.z >> 24], 1); csr_col[pos] = (int)(v.z & 0x00FFFFFFu); }
            if (base4 + 3 < rc) { pos = atomicAdd(&lcur[v.w >> 24], 1); csr_col[pos] = (int)(v.w & 0x00FFFFFFu); }
        }
    }
}

// ---------------- standalone GEMM (layer 1, dinv-scaled) ----------------

__global__ __launch_bounds__(256) void k_gemm_mfma(const void* __restrict__ Ain,
                                                   const unsigned short* __restrict__ Wt,
                                                   const float* __restrict__ bias,
                                                   const float* __restrict__ dinv,
                                                   unsigned int* __restrict__ outp, int n, int af32) {
    __shared__ __align__(16) char smem[GSMEM];
    gemm_body(smem, Ain, Wt, bias, dinv, outp, n, af32, 1, blockIdx.x);
}

// ---------------- Aggregation: SPLIT kernels (lean codegen per mode) ----------------

#define UACC(U) { float p_, q_; \
    bf2f(U.x, p_, q_); acc0 += p_; acc1 += q_; \
    bf2f(U.y, p_, q_); acc2 += p_; acc3 += q_; \
    bf2f(U.z, p_, q_); acc4 += p_; acc5 += q_; \
    bf2f(U.w, p_, q_); acc6 += p_; acc7 += q_; }

#define UACCD(U, DJ) { float p_, q_; \
    bf2f(U.x, p_, q_); acc0 = fmaf(p_, DJ, acc0); acc1 = fmaf(q_, DJ, acc1); \
    bf2f(U.y, p_, q_); acc2 = fmaf(p_, DJ, acc2); acc3 = fmaf(q_, DJ, acc3); \
    bf2f(U.z, p_, q_); acc4 = fmaf(p_, DJ, acc4); acc5 = fmaf(q_, DJ, acc5); \
    bf2f(U.w, p_, q_); acc6 = fmaf(p_, DJ, acc6); acc7 = fmaf(q_, DJ, acc7); }

// layer 0: hs raw; out_i = relu(di*(di*h_i + sum_j dj*h_j)) -> packed bf16
__global__ __launch_bounds__(256) void k_agg0(const unsigned int* __restrict__ hs,
                                              const uint2* __restrict__ rse,
                                              const int* __restrict__ csr_col, const float* __restrict__ dinv,
                                              unsigned int* __restrict__ out, int n) {
    int w = (blockIdx.x * 256 + threadIdx.x) >> 6;
    int lane = threadIdx.x & 63;
    if (w >= n) return;
    const int quad = lane >> 4;
    const int lq = lane & 15;

    const uint2 se = rse[w];
    int e = (int)se.x;
    const int end = (int)se.y;
    const float di = dinv[w];

    uint4 sv = make_uint4(0u, 0u, 0u, 0u);
    if (quad == 0) sv = *(const uint4*)&hs[(size_t)w * 64 + lq * 4];
    float acc0, acc1, acc2, acc3, acc4, acc5, acc6, acc7;
    bf2f(sv.x, acc0, acc1);
    bf2f(sv.y, acc2, acc3);
    bf2f(sv.z, acc4, acc5);
    bf2f(sv.w, acc6, acc7);
    acc0 *= di; acc1 *= di; acc2 *= di; acc3 *= di;
    acc4 *= di; acc5 *= di; acc6 *= di; acc7 *= di;

    const int zrow = n;  // zeros row (dinv[n]=0)

    while (e < end) {
        int cnt = end - e;
        if (cnt > 64) cnt = 64;
        int jv = (e + lane < end) ? csr_col[e + lane] : zrow;
        int nb8 = (cnt + 7) >> 3;
        for (int t = 0; t < nb8; t++) {
            int i0 = t * 8 + quad;
            int j0 = __shfl(jv, i0, 64);
            int j1 = __shfl(jv, i0 + 4, 64);
            uint4 u0 = *(const uint4*)&hs[(size_t)j0 * 64 + lq * 4];
            uint4 u1 = *(const uint4*)&hs[(size_t)j1 * 64 + lq * 4];
            float dj0 = dinv[j0];
            float dj1 = dinv[j1];
            UACCD(u0, dj0)
            UACCD(u1, dj1)
        }
        e += cnt;
    }

    acc0 += __shfl_xor(acc0, 16, 64); acc0 += __shfl_xor(acc0, 32, 64);
    acc1 += __shfl_xor(acc1, 16, 64); acc1 += __shfl_xor(acc1, 32, 64);
    acc2 += __shfl_xor(acc2, 16, 64); acc2 += __shfl_xor(acc2, 32, 64);
    acc3 += __shfl_xor(acc3, 16, 64); acc3 += __shfl_xor(acc3, 32, 64);
    acc4 += __shfl_xor(acc4, 16, 64); acc4 += __shfl_xor(acc4, 32, 64);
    acc5 += __shfl_xor(acc5, 16, 64); acc5 += __shfl_xor(acc5, 32, 64);
    acc6 += __shfl_xor(acc6, 16, 64); acc6 += __shfl_xor(acc6, 32, 64);
    acc7 += __shfl_xor(acc7, 16, 64); acc7 += __shfl_xor(acc7, 32, 64);

    acc0 *= di; acc1 *= di; acc2 *= di; acc3 *= di;
    acc4 *= di; acc5 *= di; acc6 *= di; acc7 *= di;
    acc0 = fmaxf(acc0, 0.f); acc1 = fmaxf(acc1, 0.f);
    acc2 = fmaxf(acc2, 0.f); acc3 = fmaxf(acc3, 0.f);
    acc4 = fmaxf(acc4, 0.f); acc5 = fmaxf(acc5, 0.f);
    acc6 = fmaxf(acc6, 0.f); acc7 = fmaxf(acc7, 0.f);

    if (quad == 0) {
        uint4 o;
        o.x = (unsigned int)f2bf(acc0) | ((unsigned int)f2bf(acc1) << 16);
        o.y = (unsigned int)f2bf(acc2) | ((unsigned int)f2bf(acc3) << 16);
        o.z = (unsigned int)f2bf(acc4) | ((unsigned int)f2bf(acc5) << 16);
        o.w = (unsigned int)f2bf(acc6) | ((unsigned int)f2bf(acc7) << 16);
        *(uint4*)&out[(size_t)w * 64 + lq * 4] = o;
    }
}

// layer 1: hs pre-scaled; out_i = log_softmax(di*(h_i + sum h_j)) -> fp32
__global__ __launch_bounds__(256) void k_agg1(const unsigned int* __restrict__ hs,
                                              const uint2* __restrict__ rse,
                                              const int* __restrict__ csr_col, const float* __restrict__ dinv,
                                              float* __restrict__ out, int n) {
    int w = (blockIdx.x * 256 + threadIdx.x) >> 6;
    int lane = threadIdx.x & 63;
    if (w >= n) return;
    const int quad = lane >> 4;
    const int lq = lane & 15;

    const uint2 se = rse[w];
    int e = (int)se.x;
    const int end = (int)se.y;
    const float di = dinv[w];

    uint4 sv = make_uint4(0u, 0u, 0u, 0u);
    if (quad == 0) sv = *(const uint4*)&hs[(size_t)w * 64 + lq * 4];
    float acc0, acc1, acc2, acc3, acc4, acc5, acc6, acc7;
    bf2f(sv.x, acc0, acc1);
    bf2f(sv.y, acc2, acc3);
    bf2f(sv.z, acc4, acc5);
    bf2f(sv.w, acc6, acc7);

    const int zrow = n;  // zeros row

    while (e < end) {
        int cnt = end - e;
        if (cnt > 64) cnt = 64;
        int jv = (e + lane < end) ? csr_col[e + lane] : zrow;
        int nb8 = (cnt + 7) >> 3;
        for (int t = 0; t < nb8; t++) {
            int i0 = t * 8 + quad;
            int j0 = __shfl(jv, i0, 64);
            int j1 = __shfl(jv, i0 + 4, 64);
            uint4 u0 = *(const uint4*)&hs[(size_t)j0 * 64 + lq * 4];
            uint4 u1 = *(const uint4*)&hs[(size_t)j1 * 64 + lq * 4];
            UACC(u0)
            UACC(u1)
        }
        e += cnt;
    }

    acc0 += __shfl_xor(acc0, 16, 64); acc0 += __shfl_xor(acc0, 32, 64);
    acc1 += __shfl_xor(acc1, 16, 64); acc1 += __shfl_xor(acc1, 32, 64);
    acc2 += __shfl_xor(acc2, 16, 64); acc2 += __shfl_xor(acc2, 32, 64);
    acc3 += __shfl_xor(acc3, 16, 64); acc3 += __shfl_xor(acc3, 32, 64);
    acc4 += __shfl_xor(acc4, 16, 64); acc4 += __shfl_xor(acc4, 32, 64);
    acc5 += __shfl_xor(acc5, 16, 64); acc5 += __shfl_xor(acc5, 32, 64);
    acc6 += __shfl_xor(acc6, 16, 64); acc6 += __shfl_xor(acc6, 32, 64);
    acc7 += __shfl_xor(acc7, 16, 64); acc7 += __shfl_xor(acc7, 32, 64);

    acc0 *= di; acc1 *= di; acc2 *= di; acc3 *= di;
    acc4 *= di; acc5 *= di; acc6 *= di; acc7 *= di;

    float m = fmaxf(fmaxf(fmaxf(acc0, acc1), fmaxf(acc2, acc3)),
                    fmaxf(fmaxf(acc4, acc5), fmaxf(acc6, acc7)));
#pragma unroll
    for (int off = 1; off < 16; off <<= 1) m = fmaxf(m, __shfl_xor(m, off, 64));
    float s = ((expf(acc0 - m) + expf(acc1 - m)) + (expf(acc2 - m) + expf(acc3 - m))) +
              ((expf(acc4 - m) + expf(acc5 - m)) + (expf(acc6 - m) + expf(acc7 - m)));
#pragma unroll
    for (int off = 1; off < 16; off <<= 1) s += __shfl_xor(s, off, 64);
    float lg = m + logf(s);
    acc0 -= lg; acc1 -= lg; acc2 -= lg; acc3 -= lg;
    acc4 -= lg; acc5 -= lg; acc6 -= lg; acc7 -= lg;

    if (quad < 2) {
        float4 o = quad ? make_float4(acc4, acc5, acc6, acc7)
                        : make_float4(acc0, acc1, acc2, acc3);
        *(float4*)&out[(size_t)w * 128 + lq * 8 + quad * 4] = o;
    }
}

// ---------------- launch ----------------

extern "C" void kernel_launch(void* const* d_in, const int* in_sizes, int n_in,
                              void* d_out, int out_size, void* d_ws, size_t ws_size,
                              hipStream_t stream) {
    const float* x  = (const float*)d_in[0];
    const float* W0 = (const float*)d_in[1];
    const float* b0 = (const float*)d_in[2];
    const float* W1 = (const float*)d_in[3];
    const float* b1 = (const float*)d_in[4];
    const int* row  = (const int*)d_in[5];
    const int* col  = (const int*)d_in[6];
    float* out = (float*)d_out;

    const int N = in_sizes[0] / FDIM;
    const int E = in_sizes[5];
    const int NB = (N + RPB - 1) / RPB;  // buckets (391 for N=100000)

    char* w = (char*)d_ws;
    size_t off = 0;
    auto alloc = [&](size_t bytes) {
        char* p = w + off;
        off += (bytes + 255) & ~(size_t)255;
        return p;
    };
    int* rbCnt   = (int*)alloc((size_t)NB * NSUB * BSTRIDE * 4);
    int* cbCnt   = (int*)alloc((size_t)NB * NSUB * BSTRIDE * 4);
    float* dinv  = (float*)alloc((size_t)(N + 1) * 4);   // +1: dinv[N]=0 for padding rows
    uint2* rse   = (uint2*)alloc((size_t)N * 8);
    int* csr_col = (int*)alloc((size_t)NB * CAP * 4);
    unsigned short* W0t = (unsigned short*)alloc((size_t)FDIM * FDIM * 2);
    unsigned short* W1t = (unsigned short*)alloc((size_t)FDIM * FDIM * 2);
    unsigned int* hs = (unsigned int*)alloc((size_t)(N + 1) * 64 * 4);  // packed bf16 hs + zero row
    // Union region: pairs+clocal (CSR build) -> hb (agg0 output, consumed by gemm1).
    size_t pairsSz = (size_t)NB * CAP * 4;
    size_t clocSz  = (size_t)NB * CAP;
    size_t uniSz   = pairsSz + clocSz + 512;
    size_t hbSz    = (size_t)N * 64 * 4;
    char* uni = (char*)alloc(uniSz > hbSz ? uniSz : hbSz);
    unsigned int* pairs = (unsigned int*)uni;
    unsigned char* clocal = (unsigned char*)(uni + pairsSz);
    unsigned int* hb = (unsigned int*)uni;   // bf16-packed h (layer-0 output)

    const int gW = (N * 64 + 255) / 256;   // wave-per-node grid
    const int gG = (N + 127) / 128;        // mfma-gemm grid

    // init, FUSED [scatter || gemm0_raw], vectorized sort+dinv
    k_init<<<16, 256, 0, stream>>>(rbCnt, cbCnt, NB, hs + (size_t)N * 64, dinv + N, W0, W1, W0t, W1t);
    k_scatter_gemm<<<NBLK + gG, 256, 0, stream>>>(row, col, rbCnt, cbCnt, pairs, clocal, E, NB,
                                                  x, W0t, b0, hs, N);
    k_sortdinv<<<NB, 512, 0, stream>>>(rbCnt, cbCnt, pairs, clocal, rse, dinv, csr_col, N, NB);

    // layer 0 agg (raw hs, per-edge dinv, relu) -> hb
    k_agg0<<<gW, 256, 0, stream>>>(hs, rse, csr_col, dinv, hb, N);

    // layer 1: hs1 = bf16((hb@W1 + b1)*dinv) ; agg(+log_softmax) -> out
    k_gemm_mfma<<<gG, 256, 0, stream>>>((const void*)hb, W1t, b1, dinv, hs, N, 0);
    k_agg1<<<gW, 256, 0, stream>>>(hs, rse, csr_col, dinv, out, N);
}